// Round 1
// baseline (118.900 us; speedup 1.0000x reference)
//
#include <hip/hip_runtime.h>
#include <hip/hip_bf16.h>

// CosSim_Loss: pred [32, 8, 512, 512] f32 -> scalar mean of per-batch 8x8
// cosine-similarity Gram matrices (diag forced to 1).
//
// ws layout: float ws[32][36]; k=0..7 -> sumsq(row i); k=8..35 -> dot(i,j), i<j.

#define NB 32      // batches
#define NM 8       // maps per batch
#define L4 65536   // (512*512)/4 float4 per row
#define NACC 36    // 8 norms + 28 pairs

__global__ __launch_bounds__(256) void cossim_partial(
    const float4* __restrict__ x, float* __restrict__ ws) {
    const int b = blockIdx.y;
    const float4* base = x + (size_t)b * NM * L4;

    float acc[NACC];
    #pragma unroll
    for (int k = 0; k < NACC; ++k) acc[k] = 0.0f;

    const int nthreads = gridDim.x * blockDim.x;   // 8192
    int l = blockIdx.x * blockDim.x + threadIdx.x;

    for (; l < L4; l += nthreads) {
        float4 v[NM];
        #pragma unroll
        for (int i = 0; i < NM; ++i) v[i] = base[(size_t)i * L4 + l];

        #pragma unroll
        for (int i = 0; i < NM; ++i) {
            acc[i] += v[i].x * v[i].x + v[i].y * v[i].y
                    + v[i].z * v[i].z + v[i].w * v[i].w;
        }
        int k = NM;
        #pragma unroll
        for (int i = 0; i < NM; ++i) {
            #pragma unroll
            for (int j = i + 1; j < NM; ++j) {
                acc[k] += v[i].x * v[j].x + v[i].y * v[j].y
                        + v[i].z * v[j].z + v[i].w * v[j].w;
                ++k;
            }
        }
    }

    // wave64 shuffle reduction per accumulator, then one atomic per wave
    #pragma unroll
    for (int k = 0; k < NACC; ++k) {
        float s = acc[k];
        #pragma unroll
        for (int off = 32; off > 0; off >>= 1) s += __shfl_down(s, off, 64);
        if ((threadIdx.x & 63) == 0) atomicAdd(&ws[b * NACC + k], s);
    }
}

__global__ __launch_bounds__(64) void cossim_finalize(
    const float* __restrict__ ws, float* __restrict__ out) {
    const int b = threadIdx.x;
    float bs = 0.0f;
    if (b < NB) {
        const float* w = ws + b * NACC;
        float n[NM];
        #pragma unroll
        for (int i = 0; i < NM; ++i) n[i] = fmaxf(sqrtf(w[i]), 1e-8f);
        float s = 0.0f;
        int k = NM;
        #pragma unroll
        for (int i = 0; i < NM; ++i) {
            #pragma unroll
            for (int j = i + 1; j < NM; ++j) {
                s += w[k] / (n[i] * n[j]);
                ++k;
            }
        }
        bs = 2.0f * s + (float)NM;   // off-diag (both triangles) + diag of ones
    }
    #pragma unroll
    for (int off = 32; off > 0; off >>= 1) bs += __shfl_down(bs, off, 64);
    if (threadIdx.x == 0) out[0] = bs / (float)(NB * NM * NM);
}

extern "C" void kernel_launch(void* const* d_in, const int* in_sizes, int n_in,
                              void* d_out, int out_size, void* d_ws, size_t ws_size,
                              hipStream_t stream) {
    const float4* x = (const float4*)d_in[0];
    float* out = (float*)d_out;
    float* ws = (float*)d_ws;

    hipMemsetAsync(ws, 0, NB * NACC * sizeof(float), stream);

    dim3 grid(32, NB);   // 32 chunks per batch x 32 batches
    cossim_partial<<<grid, 256, 0, stream>>>(x, ws);
    cossim_finalize<<<1, 64, 0, stream>>>(ws, out);
}

// Round 2
// 58.286 us; speedup vs baseline: 2.0399x; 2.0399x over previous
//
#include <hip/hip_runtime.h>
#include <hip/hip_bf16.h>

// CosSim_Loss: pred [32, 8, 512, 512] f32 -> scalar mean of per-batch 8x8
// cosine-similarity Gram matrices (diag forced to 1).
//
// ws layout: float ws[32][36]; k=0..7 -> sumsq(row i); k=8..35 -> dot(i,j), i<j.
//
// Round-2 theory: round-1 was latency-bound (VGPR=64 serialized the 8-stream
// loads; only 16 waves/CU resident). Fix: register headroom via
// __launch_bounds__(256,2) + explicit double-buffered prefetch (16 float4 in
// flight per thread) + 2x grid.

#define NB 32      // batches
#define NM 8       // maps per batch
#define L4 65536   // (512*512)/4 float4 per row
#define NACC 36    // 8 norms + 28 pairs
#define GX 64      // blocks per batch
#define ITERS 4    // L4 / (GX*256)

__global__ __launch_bounds__(256, 2) void cossim_partial(
    const float4* __restrict__ x, float* __restrict__ ws) {
    const int b = blockIdx.y;
    const float4* base = x + (size_t)b * NM * L4;

    float acc[NACC];
    #pragma unroll
    for (int k = 0; k < NACC; ++k) acc[k] = 0.0f;

    const int nthreads = GX * 256;   // 16384 threads per batch
    int l = blockIdx.x * blockDim.x + threadIdx.x;

    float4 cur[NM], nxt[NM];
    #pragma unroll
    for (int i = 0; i < NM; ++i) cur[i] = base[(size_t)i * L4 + l];

    #pragma unroll
    for (int it = 0; it < ITERS; ++it) {
        const int ln = l + nthreads;
        if (it < ITERS - 1) {
            #pragma unroll
            for (int i = 0; i < NM; ++i) nxt[i] = base[(size_t)i * L4 + ln];
        }

        #pragma unroll
        for (int i = 0; i < NM; ++i) {
            acc[i] += cur[i].x * cur[i].x + cur[i].y * cur[i].y
                    + cur[i].z * cur[i].z + cur[i].w * cur[i].w;
        }
        int k = NM;
        #pragma unroll
        for (int i = 0; i < NM; ++i) {
            #pragma unroll
            for (int j = i + 1; j < NM; ++j) {
                acc[k] += cur[i].x * cur[j].x + cur[i].y * cur[j].y
                        + cur[i].z * cur[j].z + cur[i].w * cur[j].w;
                ++k;
            }
        }

        if (it < ITERS - 1) {
            #pragma unroll
            for (int i = 0; i < NM; ++i) cur[i] = nxt[i];
        }
        l = ln;
    }

    // wave64 shuffle reduction per accumulator
    #pragma unroll
    for (int k = 0; k < NACC; ++k) {
        float s = acc[k];
        #pragma unroll
        for (int off = 32; off > 0; off >>= 1) s += __shfl_down(s, off, 64);
        acc[k] = s;   // valid in lane 0 of each wave
    }

    // block-level reduction in LDS: 4 waves -> 36 atomics per block
    __shared__ float red[4][NACC];
    const int wave = threadIdx.x >> 6;
    if ((threadIdx.x & 63) == 0) {
        #pragma unroll
        for (int k = 0; k < NACC; ++k) red[wave][k] = acc[k];
    }
    __syncthreads();
    if (threadIdx.x < NACC) {
        float s = red[0][threadIdx.x] + red[1][threadIdx.x]
                + red[2][threadIdx.x] + red[3][threadIdx.x];
        atomicAdd(&ws[b * NACC + threadIdx.x], s);
    }
}

__global__ __launch_bounds__(64) void cossim_finalize(
    const float* __restrict__ ws, float* __restrict__ out) {
    const int b = threadIdx.x;
    float bs = 0.0f;
    if (b < NB) {
        const float* w = ws + b * NACC;
        float n[NM];
        #pragma unroll
        for (int i = 0; i < NM; ++i) n[i] = fmaxf(sqrtf(w[i]), 1e-8f);
        float s = 0.0f;
        int k = NM;
        #pragma unroll
        for (int i = 0; i < NM; ++i) {
            #pragma unroll
            for (int j = i + 1; j < NM; ++j) {
                s += w[k] / (n[i] * n[j]);
                ++k;
            }
        }
        bs = 2.0f * s + (float)NM;   // off-diag (both triangles) + diag of ones
    }
    #pragma unroll
    for (int off = 32; off > 0; off >>= 1) bs += __shfl_down(bs, off, 64);
    if (threadIdx.x == 0) out[0] = bs / (float)(NB * NM * NM);
}

extern "C" void kernel_launch(void* const* d_in, const int* in_sizes, int n_in,
                              void* d_out, int out_size, void* d_ws, size_t ws_size,
                              hipStream_t stream) {
    const float4* x = (const float4*)d_in[0];
    float* out = (float*)d_out;
    float* ws = (float*)d_ws;

    hipMemsetAsync(ws, 0, NB * NACC * sizeof(float), stream);

    dim3 grid(GX, NB);   // 64 chunks per batch x 32 batches = 2048 blocks
    cossim_partial<<<grid, 256, 0, stream>>>(x, ws);
    cossim_finalize<<<1, 64, 0, stream>>>(ws, out);
}

// Round 3
// 54.305 us; speedup vs baseline: 2.1895x; 1.0733x over previous
//
#include <hip/hip_runtime.h>
#include <hip/hip_bf16.h>

// CosSim_Loss: pred [32, 8, 512, 512] f32 -> scalar mean of per-batch 8x8
// cosine-similarity Gram matrices (diag forced to 1).
//
// Round-3: remove memset+atomics (per-block partial slots, race-free),
// amortize the 216-shuffle wave reduction over ITERS=8, single-block finalize.
// Double-buffered 8-stream float4 loads (16 outstanding/thread) kept from R2.
//
// ws layout (direct path): float pw[NB][NACC][GX]  = 32*36*32*4 = 147456 B.

#define NB 32      // batches
#define NM 8       // maps per batch
#define L4 65536   // (512*512)/4 float4 per row
#define NACC 36    // 8 norms + 28 pairs
#define GX 32      // blocks per batch
#define ITERS 8    // L4 / (GX*256)

template <bool DIRECT>
__global__ __launch_bounds__(256, 2) void cossim_partial(
    const float4* __restrict__ x, float* __restrict__ ws) {
    const int b = blockIdx.y;
    const float4* base = x + (size_t)b * NM * L4;

    float acc[NACC];
    #pragma unroll
    for (int k = 0; k < NACC; ++k) acc[k] = 0.0f;

    const int nthreads = GX * 256;   // 8192 threads per batch
    int l = blockIdx.x * blockDim.x + threadIdx.x;

    float4 cur[NM], nxt[NM];
    #pragma unroll
    for (int i = 0; i < NM; ++i) cur[i] = base[(size_t)i * L4 + l];

    #pragma unroll
    for (int it = 0; it < ITERS; ++it) {
        const int ln = l + nthreads;
        if (it < ITERS - 1) {
            #pragma unroll
            for (int i = 0; i < NM; ++i) nxt[i] = base[(size_t)i * L4 + ln];
        }

        #pragma unroll
        for (int i = 0; i < NM; ++i) {
            acc[i] += cur[i].x * cur[i].x + cur[i].y * cur[i].y
                    + cur[i].z * cur[i].z + cur[i].w * cur[i].w;
        }
        int k = NM;
        #pragma unroll
        for (int i = 0; i < NM; ++i) {
            #pragma unroll
            for (int j = i + 1; j < NM; ++j) {
                acc[k] += cur[i].x * cur[j].x + cur[i].y * cur[j].y
                        + cur[i].z * cur[j].z + cur[i].w * cur[j].w;
                ++k;
            }
        }

        if (it < ITERS - 1) {
            #pragma unroll
            for (int i = 0; i < NM; ++i) cur[i] = nxt[i];
        }
        l = ln;
    }

    // wave64 shuffle reduction per accumulator
    #pragma unroll
    for (int k = 0; k < NACC; ++k) {
        float s = acc[k];
        #pragma unroll
        for (int off = 32; off > 0; off >>= 1) s += __shfl_down(s, off, 64);
        acc[k] = s;   // valid in lane 0 of each wave
    }

    // block-level reduction in LDS: 4 waves -> 36 values
    __shared__ float red[4][NACC];
    const int wave = threadIdx.x >> 6;
    if ((threadIdx.x & 63) == 0) {
        #pragma unroll
        for (int k = 0; k < NACC; ++k) red[wave][k] = acc[k];
    }
    __syncthreads();
    if (threadIdx.x < NACC) {
        float s = red[0][threadIdx.x] + red[1][threadIdx.x]
                + red[2][threadIdx.x] + red[3][threadIdx.x];
        if (DIRECT) {
            ws[((size_t)b * NACC + threadIdx.x) * GX + blockIdx.x] = s;
        } else {
            atomicAdd(&ws[b * NACC + threadIdx.x], s);
        }
    }
}

__device__ __forceinline__ float batch_score(const float* w) {
    // w[0..7] = sumsq, w[8..35] = cross dots (i<j)
    float n[NM];
    #pragma unroll
    for (int i = 0; i < NM; ++i) n[i] = fmaxf(sqrtf(w[i]), 1e-8f);
    float s = 0.0f;
    int k = NM;
    #pragma unroll
    for (int i = 0; i < NM; ++i) {
        #pragma unroll
        for (int j = i + 1; j < NM; ++j) {
            s += w[k] / (n[i] * n[j]);
            ++k;
        }
    }
    return 2.0f * s + (float)NM;
}

__global__ __launch_bounds__(1024) void cossim_finalize_direct(
    const float* __restrict__ pw, float* __restrict__ out) {
    __shared__ float red[NB][NACC];
    const int tid = threadIdx.x;

    for (int p = tid; p < NB * NACC; p += 1024) {
        const float* src = pw + (size_t)p * GX;
        float s = 0.0f;
        #pragma unroll
        for (int g = 0; g < GX; ++g) s += src[g];
        red[p / NACC][p % NACC] = s;
    }
    __syncthreads();

    if (tid < 64) {
        float bs = (tid < NB) ? batch_score(red[tid]) : 0.0f;
        #pragma unroll
        for (int off = 32; off > 0; off >>= 1) bs += __shfl_down(bs, off, 64);
        if (tid == 0) out[0] = bs / (float)(NB * NM * NM);
    }
}

__global__ __launch_bounds__(64) void cossim_finalize_atomic(
    const float* __restrict__ ws, float* __restrict__ out) {
    const int b = threadIdx.x;
    float bs = (b < NB) ? batch_score(ws + b * NACC) : 0.0f;
    #pragma unroll
    for (int off = 32; off > 0; off >>= 1) bs += __shfl_down(bs, off, 64);
    if (threadIdx.x == 0) out[0] = bs / (float)(NB * NM * NM);
}

extern "C" void kernel_launch(void* const* d_in, const int* in_sizes, int n_in,
                              void* d_out, int out_size, void* d_ws, size_t ws_size,
                              hipStream_t stream) {
    const float4* x = (const float4*)d_in[0];
    float* out = (float*)d_out;
    float* ws = (float*)d_ws;

    dim3 grid(GX, NB);   // 32 chunks per batch x 32 batches = 1024 blocks

    if (ws_size >= (size_t)NB * NACC * GX * sizeof(float)) {
        cossim_partial<true><<<grid, 256, 0, stream>>>(x, ws);
        cossim_finalize_direct<<<1, 1024, 0, stream>>>(ws, out);
    } else {
        hipMemsetAsync(ws, 0, NB * NACC * sizeof(float), stream);
        cossim_partial<false><<<grid, 256, 0, stream>>>(x, ws);
        cossim_finalize_atomic<<<1, 64, 0, stream>>>(ws, out);
    }
}